// Round 1
// baseline (1194.197 us; speedup 1.0000x reference)
//
#include <hip/hip_runtime.h>
#include <hip/hip_bf16.h>

#define D_MODEL 1024
#define NUM_HEADS 16
#define HEAD_DIM 64
#define BATCH 4
#define SEQ 1024
#define MTOK (BATCH * SEQ)

// ---------------------------------------------------------------------------
// GEMM: Y = X @ W^T + bias.  X:[M,K] row-major, W:[N,K] row-major (both
// k-contiguous -> coalesced).  128x128 tile, BK=16, 256 threads, 8x8 micro.
// MODE 0: Y[m*N+n]   (plain row-major)
// MODE 1: head-split Y[((b*H+h)*S + s)*Dh + d]  with b=m>>10,s=m&1023,h=n>>6,d=n&63
// ---------------------------------------------------------------------------
template <int MODE>
__global__ __launch_bounds__(256) void gemm_xwt(const float* __restrict__ X,
                                                const float* __restrict__ W,
                                                const float* __restrict__ bias,
                                                float* __restrict__ Y,
                                                int M, int N, int K) {
  __shared__ float As[16][132];  // [k][m], padded stride
  __shared__ float Bs[16][132];  // [k][n]
  const int t = threadIdx.x;
  const int m0 = blockIdx.y * 128;
  const int n0 = blockIdx.x * 128;
  const int tm = t & 15;   // micro-tile row group
  const int tn = t >> 4;   // micro-tile col group
  const int lr = t >> 1;        // load row 0..127
  const int lc = (t & 1) * 8;   // load col 0 or 8

  float acc[8][8];
#pragma unroll
  for (int i = 0; i < 8; ++i)
#pragma unroll
    for (int j = 0; j < 8; ++j) acc[i][j] = 0.0f;

  const float* xp = X + (size_t)(m0 + lr) * K + lc;
  const float* wp = W + (size_t)(n0 + lr) * K + lc;

  for (int kt = 0; kt < K; kt += 16) {
    float4 xa = *(const float4*)(xp + kt);
    float4 xb = *(const float4*)(xp + kt + 4);
    float4 wa = *(const float4*)(wp + kt);
    float4 wb = *(const float4*)(wp + kt + 4);
    __syncthreads();  // previous tile's compute done before overwrite
    As[lc + 0][lr] = xa.x; As[lc + 1][lr] = xa.y;
    As[lc + 2][lr] = xa.z; As[lc + 3][lr] = xa.w;
    As[lc + 4][lr] = xb.x; As[lc + 5][lr] = xb.y;
    As[lc + 6][lr] = xb.z; As[lc + 7][lr] = xb.w;
    Bs[lc + 0][lr] = wa.x; Bs[lc + 1][lr] = wa.y;
    Bs[lc + 2][lr] = wa.z; Bs[lc + 3][lr] = wa.w;
    Bs[lc + 4][lr] = wb.x; Bs[lc + 5][lr] = wb.y;
    Bs[lc + 6][lr] = wb.z; Bs[lc + 7][lr] = wb.w;
    __syncthreads();
#pragma unroll
    for (int k = 0; k < 16; ++k) {
      float a[8], b[8];
      *(float4*)&a[0] = *(float4*)&As[k][tm * 8];
      *(float4*)&a[4] = *(float4*)&As[k][tm * 8 + 4];
      *(float4*)&b[0] = *(float4*)&Bs[k][tn * 8];
      *(float4*)&b[4] = *(float4*)&Bs[k][tn * 8 + 4];
#pragma unroll
      for (int i = 0; i < 8; ++i)
#pragma unroll
        for (int j = 0; j < 8; ++j) acc[i][j] += a[i] * b[j];
    }
  }

#pragma unroll
  for (int i = 0; i < 8; ++i) {
    const int m = m0 + tm * 8 + i;
#pragma unroll
    for (int j4 = 0; j4 < 2; ++j4) {
      const int n = n0 + tn * 8 + j4 * 4;
      float4 bv = *(const float4*)(bias + n);
      float4 v;
      v.x = acc[i][j4 * 4 + 0] + bv.x;
      v.y = acc[i][j4 * 4 + 1] + bv.y;
      v.z = acc[i][j4 * 4 + 2] + bv.z;
      v.w = acc[i][j4 * 4 + 3] + bv.w;
      if (MODE == 0) {
        *(float4*)&Y[(size_t)m * N + n] = v;
      } else {
        const int b_ = m >> 10, s_ = m & 1023, h = n >> 6, d = n & 63;
        *(float4*)&Y[(((size_t)(b_ * NUM_HEADS + h)) * SEQ + s_) * HEAD_DIM + d] = v;
      }
    }
  }
}

// ---------------------------------------------------------------------------
// Attention: one block = (b*H+h, 16 q-rows).  256 threads.
// Thread t owns q-row r=t&15; within each 64-wide kv tile it computes the 4
// columns g*4..g*4+3 (g=t>>4).  Scores for the whole row (64 per thread) stay
// in registers; exact softmax (max then sum) via small LDS reductions; probs
// written to `attn` (output 1); PV accumulated with ownership (r, d=g*4..+3).
// ---------------------------------------------------------------------------
__global__ __launch_bounds__(256) void attn_kernel(const float* __restrict__ Qh,
                                                   const float* __restrict__ Kh,
                                                   const float* __restrict__ Vh,
                                                   float* __restrict__ attn,
                                                   float* __restrict__ outh) {
  const int t = threadIdx.x;
  const int bh = blockIdx.y;           // b*16 + h
  const int q0 = blockIdx.x * 16;
  const int r = t & 15;
  const int g = t >> 4;

  __shared__ float Ks[64][68];         // K tile, then reused for V tile
  __shared__ float Ps[16][68];         // normalized probs for current tile
  __shared__ float red[16][17];        // row reductions

  float q[64], sc[64];
  const float* qp = Qh + ((size_t)bh * SEQ + q0 + r) * HEAD_DIM;
#pragma unroll
  for (int i = 0; i < 16; ++i) {
    float4 v = *(const float4*)(qp + i * 4);
    q[i * 4 + 0] = v.x * 0.125f;       // scale = 1/sqrt(64)
    q[i * 4 + 1] = v.y * 0.125f;
    q[i * 4 + 2] = v.z * 0.125f;
    q[i * 4 + 3] = v.w * 0.125f;
  }

  const float* kbase = Kh + (size_t)bh * SEQ * HEAD_DIM;
  const float* vbase = Vh + (size_t)bh * SEQ * HEAD_DIM;

  // ---- score phase: sc[tile*4+j] = (Q K^T)[r][tile*64 + g*4 + j] ----
#pragma unroll
  for (int tile = 0; tile < 16; ++tile) {
    const int c0 = tile * 64;
    __syncthreads();
#pragma unroll
    for (int i = 0; i < 4; ++i) {
      const int f = t + 256 * i;       // 0..1023
      const int row = f >> 4;
      const int c4 = (f & 15) * 4;
      *(float4*)&Ks[row][c4] = *(const float4*)(kbase + (size_t)(c0 + row) * HEAD_DIM + c4);
    }
    __syncthreads();
    float s0 = 0.f, s1 = 0.f, s2 = 0.f, s3 = 0.f;
#pragma unroll
    for (int d4 = 0; d4 < 16; ++d4) {
      float4 k0 = *(float4*)&Ks[g * 4 + 0][d4 * 4];
      float4 k1 = *(float4*)&Ks[g * 4 + 1][d4 * 4];
      float4 k2 = *(float4*)&Ks[g * 4 + 2][d4 * 4];
      float4 k3 = *(float4*)&Ks[g * 4 + 3][d4 * 4];
      const float q0v = q[d4 * 4 + 0], q1v = q[d4 * 4 + 1];
      const float q2v = q[d4 * 4 + 2], q3v = q[d4 * 4 + 3];
      s0 += q0v * k0.x + q1v * k0.y + q2v * k0.z + q3v * k0.w;
      s1 += q0v * k1.x + q1v * k1.y + q2v * k1.z + q3v * k1.w;
      s2 += q0v * k2.x + q1v * k2.y + q2v * k2.z + q3v * k2.w;
      s3 += q0v * k3.x + q1v * k3.y + q2v * k3.z + q3v * k3.w;
    }
    sc[tile * 4 + 0] = s0; sc[tile * 4 + 1] = s1;
    sc[tile * 4 + 2] = s2; sc[tile * 4 + 3] = s3;
  }

  // ---- softmax over the full row (exact, two-phase) ----
  float mx = sc[0];
#pragma unroll
  for (int i = 1; i < 64; ++i) mx = fmaxf(mx, sc[i]);
  __syncthreads();
  red[r][g] = mx;
  __syncthreads();
#pragma unroll
  for (int i = 0; i < 16; ++i) mx = fmaxf(mx, red[r][i]);
  __syncthreads();
  float lsum = 0.f;
#pragma unroll
  for (int i = 0; i < 64; ++i) {
    const float e = __expf(sc[i] - mx);
    sc[i] = e;
    lsum += e;
  }
  red[r][g] = lsum;
  __syncthreads();
  float tot = 0.f;
#pragma unroll
  for (int i = 0; i < 16; ++i) tot += red[r][i];
  const float inv = 1.0f / tot;

  // ---- PV + attention-output phase ----
  float4 oacc = {0.f, 0.f, 0.f, 0.f};
#pragma unroll
  for (int tile = 0; tile < 16; ++tile) {
    const int c0 = tile * 64;
    __syncthreads();
#pragma unroll
    for (int i = 0; i < 4; ++i) {
      const int f = t + 256 * i;
      const int row = f >> 4;
      const int c4 = (f & 15) * 4;
      *(float4*)&Ks[row][c4] = *(const float4*)(vbase + (size_t)(c0 + row) * HEAD_DIM + c4);
    }
    Ps[r][g * 4 + 0] = sc[tile * 4 + 0] * inv;
    Ps[r][g * 4 + 1] = sc[tile * 4 + 1] * inv;
    Ps[r][g * 4 + 2] = sc[tile * 4 + 2] * inv;
    Ps[r][g * 4 + 3] = sc[tile * 4 + 3] * inv;
    __syncthreads();
    // coalesced write of the 16x64 prob tile (output 1)
    {
      const int ar = g;         // 0..15
      const int ac = r * 4;     // 0..60
      float4 pv = *(float4*)&Ps[ar][ac];
      *(float4*)&attn[((size_t)bh << 20) + ((size_t)(q0 + ar) << 10) + c0 + ac] = pv;
    }
    // PV: out[r][g*4..+3] += sum_c P[r][c] * V[c][g*4..+3]
#pragma unroll
    for (int c = 0; c < 64; ++c) {
      const float p = Ps[r][c];
      float4 vv = *(float4*)&Ks[c][g * 4];
      oacc.x += p * vv.x; oacc.y += p * vv.y;
      oacc.z += p * vv.z; oacc.w += p * vv.w;
    }
  }
  const int b_ = bh >> 4, h_ = bh & 15;
  *(float4*)&outh[((size_t)(b_ * SEQ + q0 + r)) * D_MODEL + h_ * HEAD_DIM + g * 4] = oacc;
}

// ---------------------------------------------------------------------------
extern "C" void kernel_launch(void* const* d_in, const int* in_sizes, int n_in,
                              void* d_out, int out_size, void* d_ws, size_t ws_size,
                              hipStream_t stream) {
  const float* query = (const float*)d_in[0];
  const float* key_  = (const float*)d_in[1];
  const float* value = (const float*)d_in[2];
  const float* Wq = (const float*)d_in[3];
  const float* bq = (const float*)d_in[4];
  const float* Wk = (const float*)d_in[5];
  const float* bk = (const float*)d_in[6];
  const float* Wv = (const float*)d_in[7];
  const float* bv = (const float*)d_in[8];
  const float* Wo = (const float*)d_in[9];
  const float* bo = (const float*)d_in[10];

  float* out0 = (float*)d_out;                         // [4096,1024]
  float* attn = out0 + (size_t)MTOK * D_MODEL;         // [4,16,1024,1024]

  const size_t SEG = (size_t)MTOK * D_MODEL;           // 4,194,304 floats
  float* Qh   = (float*)d_ws;                          // [B,H,S,Dh]
  float* Kh   = Qh + SEG;
  float* Vh   = Kh + SEG;
  float* OutH = Vh + SEG;                              // [B,S,D]

  dim3 tB(256);
  dim3 gG(D_MODEL / 128, MTOK / 128);                  // (8,32)
  hipLaunchKernelGGL((gemm_xwt<1>), gG, tB, 0, stream, query, Wq, bq, Qh, MTOK, D_MODEL, D_MODEL);
  hipLaunchKernelGGL((gemm_xwt<1>), gG, tB, 0, stream, key_,  Wk, bk, Kh, MTOK, D_MODEL, D_MODEL);
  hipLaunchKernelGGL((gemm_xwt<1>), gG, tB, 0, stream, value, Wv, bv, Vh, MTOK, D_MODEL, D_MODEL);

  dim3 gA(SEQ / 16, BATCH * NUM_HEADS);                // (64,64)
  hipLaunchKernelGGL(attn_kernel, gA, tB, 0, stream, Qh, Kh, Vh, attn, OutH);

  hipLaunchKernelGGL((gemm_xwt<0>), gG, tB, 0, stream, OutH, Wo, bo, out0, MTOK, D_MODEL, D_MODEL);
}

// Round 2
// 330.270 us; speedup vs baseline: 3.6158x; 3.6158x over previous
//
#include <hip/hip_runtime.h>
#include <hip/hip_bf16.h>

#define NH 16
#define S 1024
#define DH 64
#define DM 1024
#define NB 4
#define MTOK 4096

typedef __attribute__((ext_vector_type(8))) short bf16x8;
typedef __attribute__((ext_vector_type(4))) float f32x4;
typedef __attribute__((ext_vector_type(8))) unsigned short u16x8;

__device__ inline unsigned short f2bf(float x) {
  __hip_bfloat16 h = __float2bfloat16(x);
  return __builtin_bit_cast(unsigned short, h);
}

// ---------------------------------------------------------------------------
// fp32 -> bf16 (vectorized, 8 elems/thread)
// ---------------------------------------------------------------------------
__global__ __launch_bounds__(256) void cvt_kernel(const float* __restrict__ src,
                                                  unsigned short* __restrict__ dst,
                                                  int n8) {
  int i = blockIdx.x * 256 + threadIdx.x;
  if (i >= n8) return;
  const float4* s4 = (const float4*)(src + (size_t)i * 8);
  float4 v0 = s4[0], v1 = s4[1];
  u16x8 o;
  o[0] = f2bf(v0.x); o[1] = f2bf(v0.y); o[2] = f2bf(v0.z); o[3] = f2bf(v0.w);
  o[4] = f2bf(v1.x); o[5] = f2bf(v1.y); o[6] = f2bf(v1.z); o[7] = f2bf(v1.w);
  *(u16x8*)(dst + (size_t)i * 8) = o;
}

// ---------------------------------------------------------------------------
// bf16 MFMA GEMM: Y = X @ W^T + bias.  X:[M=4096][K=1024] bf16, W:[N=1024][K]
// bf16 (k-contiguous).  128x128 tile, BK=32, 256 thr = 4 waves (2x2 of 64x64),
// reg-staged LDS, 16x16x32 MFMA.
// MODE 0: fp32 row-major [M][DM]
// MODE 1: bf16 head-split [((b*16+h)*S+s)*64+d]
// MODE 2: bf16 V-transposed [((b*16+h)*64+d)*S+s]
// ---------------------------------------------------------------------------
template <int MODE>
__global__ __launch_bounds__(256) void gemm_bf16(const unsigned short* __restrict__ X,
                                                 const unsigned short* __restrict__ W,
                                                 const float* __restrict__ bias,
                                                 void* __restrict__ Yv) {
  __shared__ unsigned short As[128 * 32];
  __shared__ unsigned short Bs[128 * 32];
  const int t = threadIdx.x;
  const int l = t & 63;
  const int w = t >> 6;
  const int wr = w >> 1, wc = w & 1;
  const int cl = l & 15, kg = l >> 4;
  const int m0 = blockIdx.y * 128, n0 = blockIdx.x * 128;

  const int u0 = t, u1 = t + 256;
  const int r0 = u0 >> 2, k0 = (u0 & 3) * 8;
  const int r1 = u1 >> 2, k1 = (u1 & 3) * 8;
  const unsigned short* xa0 = X + (size_t)(m0 + r0) * DM + k0;
  const unsigned short* xa1 = X + (size_t)(m0 + r1) * DM + k1;
  const unsigned short* wb0 = W + (size_t)(n0 + r0) * DM + k0;
  const unsigned short* wb1 = W + (size_t)(n0 + r1) * DM + k1;

  f32x4 acc[4][4] = {};

  bf16x8 ra0 = *(const bf16x8*)xa0;
  bf16x8 ra1 = *(const bf16x8*)xa1;
  bf16x8 rb0 = *(const bf16x8*)wb0;
  bf16x8 rb1 = *(const bf16x8*)wb1;

  for (int kt = 0; kt < 32; ++kt) {
    __syncthreads();
    *(bf16x8*)&As[u0 * 8] = ra0;
    *(bf16x8*)&As[u1 * 8] = ra1;
    *(bf16x8*)&Bs[u0 * 8] = rb0;
    *(bf16x8*)&Bs[u1 * 8] = rb1;
    __syncthreads();
    if (kt < 31) {
      const int ko = (kt + 1) * 32;
      ra0 = *(const bf16x8*)(xa0 + ko);
      ra1 = *(const bf16x8*)(xa1 + ko);
      rb0 = *(const bf16x8*)(wb0 + ko);
      rb1 = *(const bf16x8*)(wb1 + ko);
    }
    bf16x8 a[4], b[4];
#pragma unroll
    for (int m = 0; m < 4; ++m)
      a[m] = *(const bf16x8*)&As[(wr * 64 + m * 16 + cl) * 32 + kg * 8];
#pragma unroll
    for (int n = 0; n < 4; ++n)
      b[n] = *(const bf16x8*)&Bs[(wc * 64 + n * 16 + cl) * 32 + kg * 8];
#pragma unroll
    for (int m = 0; m < 4; ++m)
#pragma unroll
      for (int n = 0; n < 4; ++n)
        acc[m][n] = __builtin_amdgcn_mfma_f32_16x16x32_bf16(a[m], b[n], acc[m][n], 0, 0, 0);
  }

#pragma unroll
  for (int i = 0; i < 4; ++i) {
#pragma unroll
    for (int j = 0; j < 4; ++j) {
      const int gmb = m0 + wr * 64 + i * 16 + kg * 4;
      const int gn = n0 + wc * 64 + j * 16 + cl;
      const float bv = bias[gn];
#pragma unroll
      for (int r = 0; r < 4; ++r) {
        const int gm = gmb + r;
        const float val = acc[i][j][r] + bv;
        if (MODE == 0) {
          ((float*)Yv)[(size_t)gm * DM + gn] = val;
        } else if (MODE == 1) {
          const int b_ = gm >> 10, s_ = gm & 1023, h_ = gn >> 6, d_ = gn & 63;
          ((unsigned short*)Yv)[((size_t)(b_ * NH + h_) * S + s_) * DH + d_] = f2bf(val);
        } else {
          const int b_ = gm >> 10, s_ = gm & 1023, h_ = gn >> 6, d_ = gn & 63;
          ((unsigned short*)Yv)[((size_t)(b_ * NH + h_) * DH + d_) * S + s_] = f2bf(val);
        }
      }
    }
  }
}

// ---------------------------------------------------------------------------
// MFMA attention.  Block = 4 waves x 16 q-rows = 64 q-rows.  Grid (16, 64).
// K/V read from global (L2-resident per head).  Two-pass exact softmax.
// ---------------------------------------------------------------------------
__global__ __launch_bounds__(256) void attn_mfma(const unsigned short* __restrict__ Qh,
                                                 const unsigned short* __restrict__ Kh,
                                                 const unsigned short* __restrict__ Vt,
                                                 float* __restrict__ attn,
                                                 unsigned short* __restrict__ OutH) {
  __shared__ unsigned short P_lds[4][16 * 48];  // per-wave [q 16][kc 32] stride 48
  const int t = threadIdx.x, l = t & 63, w = t >> 6;
  const int cl = l & 15, kg = l >> 4;
  const int bh = blockIdx.y;
  const int q0 = blockIdx.x * 64 + w * 16;

  const unsigned short* qp = Qh + ((size_t)bh * S + q0 + cl) * DH + kg * 8;
  bf16x8 aq0 = *(const bf16x8*)qp;          // d = kg*8 .. +7
  bf16x8 aq1 = *(const bf16x8*)(qp + 32);   // d = 32+kg*8 .. +7

  const unsigned short* kb = Kh + (size_t)bh * S * DH;
  const f32x4 zero = {0.f, 0.f, 0.f, 0.f};

  float m[4], sum[4];
#pragma unroll
  for (int r = 0; r < 4; ++r) { m[r] = -1e30f; sum[r] = 0.f; }

  // ---- pass A: running max/sum ----
  for (int kt = 0; kt < 64; ++kt) {
    const unsigned short* kp = kb + (size_t)(kt * 16 + cl) * DH + kg * 8;
    bf16x8 bk0 = *(const bf16x8*)kp;
    bf16x8 bk1 = *(const bf16x8*)(kp + 32);
    f32x4 sc = __builtin_amdgcn_mfma_f32_16x16x32_bf16(aq1, bk1, zero, 0, 0, 0);
    sc = __builtin_amdgcn_mfma_f32_16x16x32_bf16(aq0, bk0, sc, 0, 0, 0);
#pragma unroll
    for (int r = 0; r < 4; ++r) {
      const float s = sc[r] * 0.125f;
      float mx = s;
      mx = fmaxf(mx, __shfl_xor(mx, 1, 16));
      mx = fmaxf(mx, __shfl_xor(mx, 2, 16));
      mx = fmaxf(mx, __shfl_xor(mx, 4, 16));
      mx = fmaxf(mx, __shfl_xor(mx, 8, 16));
      const float mnew = fmaxf(m[r], mx);
      float e = __expf(s - mnew);
      e += __shfl_xor(e, 1, 16);
      e += __shfl_xor(e, 2, 16);
      e += __shfl_xor(e, 4, 16);
      e += __shfl_xor(e, 8, 16);
      sum[r] = sum[r] * __expf(m[r] - mnew) + e;
      m[r] = mnew;
    }
  }
  float inv[4];
#pragma unroll
  for (int r = 0; r < 4; ++r) inv[r] = 1.0f / sum[r];

  // ---- pass B: probs (write fp32) + PV ----
  f32x4 oacc[4] = {};
  unsigned short* pl = &P_lds[w][0];
  const unsigned short* vb = Vt + (size_t)bh * DH * S;
  float* ab = attn + ((size_t)bh << 20);

  for (int c = 0; c < 32; ++c) {
#pragma unroll
    for (int sub = 0; sub < 2; ++sub) {
      const int kc0 = c * 32 + sub * 16;
      const unsigned short* kp = kb + (size_t)(kc0 + cl) * DH + kg * 8;
      bf16x8 bk0 = *(const bf16x8*)kp;
      bf16x8 bk1 = *(const bf16x8*)(kp + 32);
      f32x4 sc = __builtin_amdgcn_mfma_f32_16x16x32_bf16(aq1, bk1, zero, 0, 0, 0);
      sc = __builtin_amdgcn_mfma_f32_16x16x32_bf16(aq0, bk0, sc, 0, 0, 0);
#pragma unroll
      for (int r = 0; r < 4; ++r) {
        const float p = __expf(sc[r] * 0.125f - m[r]) * inv[r];
        ab[((size_t)(q0 + kg * 4 + r) << 10) + kc0 + cl] = p;
        pl[(kg * 4 + r) * 48 + sub * 16 + cl] = f2bf(p);
      }
    }
    asm volatile("s_waitcnt lgkmcnt(0)" ::: "memory");
    bf16x8 pa = *(const bf16x8*)&pl[cl * 48 + kg * 8];  // A-frag: row=cl, k=kg*8+i
#pragma unroll
    for (int j = 0; j < 4; ++j) {
      const unsigned short* vp = vb + (size_t)(j * 16 + cl) * S + c * 32 + kg * 8;
      bf16x8 bvv = *(const bf16x8*)vp;
      oacc[j] = __builtin_amdgcn_mfma_f32_16x16x32_bf16(pa, bvv, oacc[j], 0, 0, 0);
    }
  }

  const int b_ = bh >> 4, h_ = bh & 15;
#pragma unroll
  for (int j = 0; j < 4; ++j)
#pragma unroll
    for (int r = 0; r < 4; ++r)
      OutH[((size_t)(b_ * S + q0 + kg * 4 + r)) * DM + h_ * DH + j * 16 + cl] =
          f2bf(oacc[j][r]);
}

// ---------------------------------------------------------------------------
extern "C" void kernel_launch(void* const* d_in, const int* in_sizes, int n_in,
                              void* d_out, int out_size, void* d_ws, size_t ws_size,
                              hipStream_t stream) {
  const float* query = (const float*)d_in[0];
  const float* key_  = (const float*)d_in[1];
  const float* value = (const float*)d_in[2];
  const float* Wq = (const float*)d_in[3];
  const float* bq = (const float*)d_in[4];
  const float* Wk = (const float*)d_in[5];
  const float* bk = (const float*)d_in[6];
  const float* Wv = (const float*)d_in[7];
  const float* bv = (const float*)d_in[8];
  const float* Wo = (const float*)d_in[9];
  const float* bo = (const float*)d_in[10];

  float* out0 = (float*)d_out;                       // [4096][1024] fp32
  float* attn = out0 + (size_t)MTOK * DM;            // [4,16,1024,1024] fp32

  const size_t M1 = 1u << 20;
  unsigned short* wsu = (unsigned short*)d_ws;
  unsigned short* Xq  = wsu;             // 4M
  unsigned short* Xk  = wsu + 4 * M1;
  unsigned short* Xv  = wsu + 8 * M1;
  unsigned short* Wqb = wsu + 12 * M1;   // 1M each
  unsigned short* Wkb = wsu + 13 * M1;
  unsigned short* Wvb = wsu + 14 * M1;
  unsigned short* Wob = wsu + 15 * M1;
  unsigned short* Qh  = wsu + 16 * M1;   // 4M each
  unsigned short* Kh  = wsu + 20 * M1;
  unsigned short* Vt  = wsu + 24 * M1;
  unsigned short* OutH= wsu + 28 * M1;

  dim3 tB(256);
  // conversions
  hipLaunchKernelGGL(cvt_kernel, dim3(2048), tB, 0, stream, query, Xq, 524288);
  hipLaunchKernelGGL(cvt_kernel, dim3(2048), tB, 0, stream, key_,  Xk, 524288);
  hipLaunchKernelGGL(cvt_kernel, dim3(2048), tB, 0, stream, value, Xv, 524288);
  hipLaunchKernelGGL(cvt_kernel, dim3(512),  tB, 0, stream, Wq, Wqb, 131072);
  hipLaunchKernelGGL(cvt_kernel, dim3(512),  tB, 0, stream, Wk, Wkb, 131072);
  hipLaunchKernelGGL(cvt_kernel, dim3(512),  tB, 0, stream, Wv, Wvb, 131072);
  hipLaunchKernelGGL(cvt_kernel, dim3(512),  tB, 0, stream, Wo, Wob, 131072);

  dim3 gG(DM / 128, MTOK / 128);  // (8, 32)
  hipLaunchKernelGGL((gemm_bf16<1>), gG, tB, 0, stream, Xq, Wqb, bq, (void*)Qh);
  hipLaunchKernelGGL((gemm_bf16<1>), gG, tB, 0, stream, Xk, Wkb, bk, (void*)Kh);
  hipLaunchKernelGGL((gemm_bf16<2>), gG, tB, 0, stream, Xv, Wvb, bv, (void*)Vt);

  hipLaunchKernelGGL(attn_mfma, dim3(16, 64), tB, 0, stream, Qh, Kh, Vt, attn, OutH);

  hipLaunchKernelGGL((gemm_bf16<0>), gG, tB, 0, stream, OutH, Wob, bo, (void*)out0);
}

// Round 3
// 242.042 us; speedup vs baseline: 4.9338x; 1.3645x over previous
//
#include <hip/hip_runtime.h>
#include <hip/hip_bf16.h>

#define NH 16
#define S 1024
#define DH 64
#define DM 1024
#define MTOK 4096

typedef __attribute__((ext_vector_type(8))) short bf16x8;
typedef __attribute__((ext_vector_type(4))) float f32x4;
typedef __attribute__((ext_vector_type(16))) float f32x16;
typedef __attribute__((ext_vector_type(8))) unsigned short u16x8;
typedef __attribute__((ext_vector_type(4))) unsigned short u16x4;

__device__ inline unsigned short f2bf(float x) {
  __hip_bfloat16 h = __float2bfloat16(x);
  return __builtin_bit_cast(unsigned short, h);
}

__device__ inline unsigned cvt_pk_bf16(float lo, float hi_) {
  unsigned r;
  asm("v_cvt_pk_bf16_f32 %0, %1, %2" : "=v"(r) : "v"(lo), "v"(hi_));
  return r;
}

// ---------------------------------------------------------------------------
// fp32 -> bf16 for all 7 tensors in one launch.
// blocks [0,6144): activations (3 x 2048); [6144,8192): weights (4 x 512).
// ---------------------------------------------------------------------------
__global__ __launch_bounds__(256) void cvt_all(
    const float* __restrict__ q, const float* __restrict__ k, const float* __restrict__ v,
    const float* __restrict__ wq, const float* __restrict__ wk,
    const float* __restrict__ wv, const float* __restrict__ wo,
    unsigned short* __restrict__ xq, unsigned short* __restrict__ xk,
    unsigned short* __restrict__ xv, unsigned short* __restrict__ wqb,
    unsigned short* __restrict__ wkb, unsigned short* __restrict__ wvb,
    unsigned short* __restrict__ wob) {
  const int bid = blockIdx.x;
  const float* src;
  unsigned short* dst;
  int lb;
  if (bid < 6144) {
    const int r = bid >> 11;
    lb = bid & 2047;
    src = (r == 0) ? q : ((r == 1) ? k : v);
    dst = (r == 0) ? xq : ((r == 1) ? xk : xv);
  } else {
    const int r = (bid - 6144) >> 9;
    lb = (bid - 6144) & 511;
    src = (r == 0) ? wq : ((r == 1) ? wk : ((r == 2) ? wv : wo));
    dst = (r == 0) ? wqb : ((r == 1) ? wkb : ((r == 2) ? wvb : wob));
  }
  const int i = lb * 256 + threadIdx.x;
  const float4* s4 = (const float4*)(src + (size_t)i * 8);
  float4 v0 = s4[0], v1 = s4[1];
  u16x8 o;
  o[0] = f2bf(v0.x); o[1] = f2bf(v0.y); o[2] = f2bf(v0.z); o[3] = f2bf(v0.w);
  o[4] = f2bf(v1.x); o[5] = f2bf(v1.y); o[6] = f2bf(v1.z); o[7] = f2bf(v1.w);
  *(u16x8*)(dst + (size_t)i * 8) = o;
}

// ---------------------------------------------------------------------------
// bf16 MFMA GEMM: Y = X @ W^T + bias.  128x128 tile, BK=32, 4 waves.
// MODE 0: fp32 row-major; MODE 1: bf16 head-split; MODE 2: bf16 V-transposed;
// MODE 3: bf16 head-split scaled by 0.125 (K projection).
// ---------------------------------------------------------------------------
template <int MODE>
__global__ __launch_bounds__(256) void gemm_bf16(const unsigned short* __restrict__ X,
                                                 const unsigned short* __restrict__ W,
                                                 const float* __restrict__ bias,
                                                 void* __restrict__ Yv) {
  __shared__ unsigned short As[128 * 32];
  __shared__ unsigned short Bs[128 * 32];
  const int t = threadIdx.x;
  const int l = t & 63;
  const int w = t >> 6;
  const int wr = w >> 1, wc = w & 1;
  const int cl = l & 15, kg = l >> 4;
  const int m0 = blockIdx.y * 128, n0 = blockIdx.x * 128;

  const int u0 = t, u1 = t + 256;
  const int r0 = u0 >> 2, k0 = (u0 & 3) * 8;
  const int r1 = u1 >> 2, k1 = (u1 & 3) * 8;
  const unsigned short* xa0 = X + (size_t)(m0 + r0) * DM + k0;
  const unsigned short* xa1 = X + (size_t)(m0 + r1) * DM + k1;
  const unsigned short* wb0 = W + (size_t)(n0 + r0) * DM + k0;
  const unsigned short* wb1 = W + (size_t)(n0 + r1) * DM + k1;

  f32x4 acc[4][4] = {};

  bf16x8 ra0 = *(const bf16x8*)xa0;
  bf16x8 ra1 = *(const bf16x8*)xa1;
  bf16x8 rb0 = *(const bf16x8*)wb0;
  bf16x8 rb1 = *(const bf16x8*)wb1;

  for (int kt = 0; kt < 32; ++kt) {
    __syncthreads();
    *(bf16x8*)&As[u0 * 8] = ra0;
    *(bf16x8*)&As[u1 * 8] = ra1;
    *(bf16x8*)&Bs[u0 * 8] = rb0;
    *(bf16x8*)&Bs[u1 * 8] = rb1;
    __syncthreads();
    if (kt < 31) {
      const int ko = (kt + 1) * 32;
      ra0 = *(const bf16x8*)(xa0 + ko);
      ra1 = *(const bf16x8*)(xa1 + ko);
      rb0 = *(const bf16x8*)(wb0 + ko);
      rb1 = *(const bf16x8*)(wb1 + ko);
    }
    bf16x8 a[4], b[4];
#pragma unroll
    for (int m = 0; m < 4; ++m)
      a[m] = *(const bf16x8*)&As[(wr * 64 + m * 16 + cl) * 32 + kg * 8];
#pragma unroll
    for (int n = 0; n < 4; ++n)
      b[n] = *(const bf16x8*)&Bs[(wc * 64 + n * 16 + cl) * 32 + kg * 8];
#pragma unroll
    for (int m = 0; m < 4; ++m)
#pragma unroll
      for (int n = 0; n < 4; ++n)
        acc[m][n] = __builtin_amdgcn_mfma_f32_16x16x32_bf16(a[m], b[n], acc[m][n], 0, 0, 0);
  }

#pragma unroll
  for (int i = 0; i < 4; ++i) {
#pragma unroll
    for (int j = 0; j < 4; ++j) {
      const int gmb = m0 + wr * 64 + i * 16 + kg * 4;
      const int gn = n0 + wc * 64 + j * 16 + cl;
      const float bv = bias[gn];
#pragma unroll
      for (int r = 0; r < 4; ++r) {
        const int gm = gmb + r;
        float val = acc[i][j][r] + bv;
        if (MODE == 3) val *= 0.125f;
        if (MODE == 0) {
          ((float*)Yv)[(size_t)gm * DM + gn] = val;
        } else if (MODE == 1 || MODE == 3) {
          const int b_ = gm >> 10, s_ = gm & 1023, h_ = gn >> 6, d_ = gn & 63;
          ((unsigned short*)Yv)[((size_t)(b_ * NH + h_) * S + s_) * DH + d_] = f2bf(val);
        } else {
          const int b_ = gm >> 10, s_ = gm & 1023, h_ = gn >> 6, d_ = gn & 63;
          ((unsigned short*)Yv)[((size_t)(b_ * NH + h_) * DH + d_) * S + s_] = f2bf(val);
        }
      }
    }
  }
}

// ---------------------------------------------------------------------------
// Swapped-MFMA attention.  Block = 4 waves; wave owns 32 q-rows (QBLK=32).
// Grid (bh=64, qt=8).  mfma_f32_32x32x16_bf16 with A=K (rows=kv), B=Q
// (cols=q): lane holds 16 kv-scores of ONE q-row -> lane-local softmax.
// K pre-scaled by 0.125.  Two-pass exact softmax; no LDS.
// ---------------------------------------------------------------------------
__global__ __launch_bounds__(256) void attn_mfma(const unsigned short* __restrict__ Qh,
                                                 const unsigned short* __restrict__ Kh,
                                                 const unsigned short* __restrict__ Vt,
                                                 float* __restrict__ attn,
                                                 unsigned short* __restrict__ OutH) {
  const int t = threadIdx.x, l = t & 63, w = t >> 6;
  const int lq = l & 31, hi = l >> 5;
  const int bh = blockIdx.x;
  const int q0 = blockIdx.y * 128 + w * 32;

  // Q as B-frags: col=lq (q-row), k=hi*8+i (d); 4 d-slices of 16.
  const unsigned short* qp = Qh + ((size_t)bh * S + q0 + lq) * DH + hi * 8;
  bf16x8 qf0 = *(const bf16x8*)(qp);
  bf16x8 qf1 = *(const bf16x8*)(qp + 16);
  bf16x8 qf2 = *(const bf16x8*)(qp + 32);
  bf16x8 qf3 = *(const bf16x8*)(qp + 48);

  const unsigned short* kb = Kh + (size_t)bh * S * DH;
  const unsigned short* vb = Vt + (size_t)bh * DH * S;

  float m = -1e30f, sum = 0.f;

  // ---- pass A: running max / sum (lane-local; no cross-lane per tile) ----
  for (int kt = 0; kt < 32; ++kt) {
    const unsigned short* kp = kb + (size_t)(kt * 32 + lq) * DH + hi * 8;
    f32x16 acc = {};
    acc = __builtin_amdgcn_mfma_f32_32x32x16_bf16(*(const bf16x8*)(kp),      qf0, acc, 0, 0, 0);
    acc = __builtin_amdgcn_mfma_f32_32x32x16_bf16(*(const bf16x8*)(kp + 16), qf1, acc, 0, 0, 0);
    acc = __builtin_amdgcn_mfma_f32_32x32x16_bf16(*(const bf16x8*)(kp + 32), qf2, acc, 0, 0, 0);
    acc = __builtin_amdgcn_mfma_f32_32x32x16_bf16(*(const bf16x8*)(kp + 48), qf3, acc, 0, 0, 0);
    float t0 = fmaxf(fmaxf(acc[0], acc[1]), fmaxf(acc[2], acc[3]));
    float t1 = fmaxf(fmaxf(acc[4], acc[5]), fmaxf(acc[6], acc[7]));
    float t2 = fmaxf(fmaxf(acc[8], acc[9]), fmaxf(acc[10], acc[11]));
    float t3 = fmaxf(fmaxf(acc[12], acc[13]), fmaxf(acc[14], acc[15]));
    const float tmax = fmaxf(fmaxf(t0, t1), fmaxf(t2, t3));
    const float mnew = fmaxf(m, tmax);
    const float f = __expf(m - mnew);
    float ls = 0.f;
#pragma unroll
    for (int r = 0; r < 16; ++r) ls += __expf(acc[r] - mnew);
    sum = sum * f + ls;
    m = mnew;
  }
  // combine lane pair (l, l^32): both halves of the 32-kv tiles, same q.
  {
    const float pm = __shfl_xor(m, 32);
    const float ps = __shfl_xor(sum, 32);
    const float M = fmaxf(m, pm);
    sum = sum * __expf(m - M) + ps * __expf(pm - M);
    m = M;
  }
  const float inv = 1.0f / sum;

  // ---- pass B: recompute scores, write normalized fp32 probs, PV ----
  f32x16 o0 = {}, o1 = {};
  float* ab = attn + ((size_t)bh << 20) + ((size_t)(q0 + lq) << 10);

  for (int kt = 0; kt < 32; ++kt) {
    const unsigned short* kp = kb + (size_t)(kt * 32 + lq) * DH + hi * 8;
    f32x16 acc = {};
    acc = __builtin_amdgcn_mfma_f32_32x32x16_bf16(*(const bf16x8*)(kp),      qf0, acc, 0, 0, 0);
    acc = __builtin_amdgcn_mfma_f32_32x32x16_bf16(*(const bf16x8*)(kp + 16), qf1, acc, 0, 0, 0);
    acc = __builtin_amdgcn_mfma_f32_32x32x16_bf16(*(const bf16x8*)(kp + 32), qf2, acc, 0, 0, 0);
    acc = __builtin_amdgcn_mfma_f32_32x32x16_bf16(*(const bf16x8*)(kp + 48), qf3, acc, 0, 0, 0);
    float p[16];
#pragma unroll
    for (int r = 0; r < 16; ++r) p[r] = __expf(acc[r] - m) * inv;

    // fp32 prob stores: reg r -> kv = (r&3) + 8*(r>>2) + 4*hi, so each group
    // of 4 regs is a contiguous float4; lanes l,l^32 + groups tile 128B rows.
#pragma unroll
    for (int g = 0; g < 4; ++g) {
      f32x4 pv = {p[4 * g], p[4 * g + 1], p[4 * g + 2], p[4 * g + 3]};
      *(f32x4*)(ab + kt * 32 + 8 * g + 4 * hi) = pv;
    }

    // P^T -> bf16 B-frags (kv slices [0,16) and [16,32)).
    unsigned wds0 = cvt_pk_bf16(p[0], p[1]),   wds1 = cvt_pk_bf16(p[2], p[3]);
    unsigned wds2 = cvt_pk_bf16(p[4], p[5]),   wds3 = cvt_pk_bf16(p[6], p[7]);
    unsigned wds4 = cvt_pk_bf16(p[8], p[9]),   wds5 = cvt_pk_bf16(p[10], p[11]);
    unsigned wds6 = cvt_pk_bf16(p[12], p[13]), wds7 = cvt_pk_bf16(p[14], p[15]);
    unsigned x0 = __shfl_xor((int)wds0, 32), x1 = __shfl_xor((int)wds1, 32);
    unsigned x2 = __shfl_xor((int)wds2, 32), x3 = __shfl_xor((int)wds3, 32);
    unsigned x4 = __shfl_xor((int)wds4, 32), x5 = __shfl_xor((int)wds5, 32);
    unsigned x6 = __shfl_xor((int)wds6, 32), x7 = __shfl_xor((int)wds7, 32);
    union UU { unsigned u[4]; bf16x8 v; } f0, f1;
    f0.u[0] = hi ? x2 : wds0;  f0.u[1] = hi ? x3 : wds1;
    f0.u[2] = hi ? wds2 : x0;  f0.u[3] = hi ? wds3 : x1;
    f1.u[0] = hi ? x6 : wds4;  f1.u[1] = hi ? x7 : wds5;
    f1.u[2] = hi ? wds6 : x4;  f1.u[3] = hi ? wds7 : x5;

    // PV: out^T[d][q] += Vt-frag x P^T-frag  (2 d-blocks x 2 kv-slices)
    {
      const unsigned short* vp = vb + (size_t)(lq)*S + kt * 32 + hi * 8;
      bf16x8 v0 = *(const bf16x8*)vp;
      bf16x8 v1 = *(const bf16x8*)(vp + 16);
      o0 = __builtin_amdgcn_mfma_f32_32x32x16_bf16(v0, f0.v, o0, 0, 0, 0);
      o0 = __builtin_amdgcn_mfma_f32_32x32x16_bf16(v1, f1.v, o0, 0, 0, 0);
    }
    {
      const unsigned short* vp = vb + (size_t)(32 + lq) * S + kt * 32 + hi * 8;
      bf16x8 v0 = *(const bf16x8*)vp;
      bf16x8 v1 = *(const bf16x8*)(vp + 16);
      o1 = __builtin_amdgcn_mfma_f32_32x32x16_bf16(v0, f0.v, o1, 0, 0, 0);
      o1 = __builtin_amdgcn_mfma_f32_32x32x16_bf16(v1, f1.v, o1, 0, 0, 0);
    }
  }

  // ---- O store: reg r of o{0,1} -> d = dblk*32 + (r&3)+8*(r>>2)+4*hi ----
  const int b_ = bh >> 4, h_ = bh & 15;
  unsigned short* op = OutH + ((size_t)(b_ * S + q0 + lq)) * DM + h_ * DH;
#pragma unroll
  for (int g = 0; g < 4; ++g) {
    u16x4 a;
    a[0] = f2bf(o0[4 * g]);     a[1] = f2bf(o0[4 * g + 1]);
    a[2] = f2bf(o0[4 * g + 2]); a[3] = f2bf(o0[4 * g + 3]);
    *(u16x4*)(op + 8 * g + 4 * hi) = a;
    u16x4 b2;
    b2[0] = f2bf(o1[4 * g]);     b2[1] = f2bf(o1[4 * g + 1]);
    b2[2] = f2bf(o1[4 * g + 2]); b2[3] = f2bf(o1[4 * g + 3]);
    *(u16x4*)(op + 32 + 8 * g + 4 * hi) = b2;
  }
}

// ---------------------------------------------------------------------------
extern "C" void kernel_launch(void* const* d_in, const int* in_sizes, int n_in,
                              void* d_out, int out_size, void* d_ws, size_t ws_size,
                              hipStream_t stream) {
  const float* query = (const float*)d_in[0];
  const float* key_  = (const float*)d_in[1];
  const float* value = (const float*)d_in[2];
  const float* Wq = (const float*)d_in[3];
  const float* bq = (const float*)d_in[4];
  const float* Wk = (const float*)d_in[5];
  const float* bk = (const float*)d_in[6];
  const float* Wv = (const float*)d_in[7];
  const float* bv = (const float*)d_in[8];
  const float* Wo = (const float*)d_in[9];
  const float* bo = (const float*)d_in[10];

  float* out0 = (float*)d_out;                // [4096][1024] fp32
  float* attn = out0 + (size_t)MTOK * DM;     // [4,16,1024,1024] fp32

  const size_t M1 = 1u << 20;
  unsigned short* wsu = (unsigned short*)d_ws;
  unsigned short* Xq  = wsu;
  unsigned short* Xk  = wsu + 4 * M1;
  unsigned short* Xv  = wsu + 8 * M1;
  unsigned short* Wqb = wsu + 12 * M1;
  unsigned short* Wkb = wsu + 13 * M1;
  unsigned short* Wvb = wsu + 14 * M1;
  unsigned short* Wob = wsu + 15 * M1;
  unsigned short* Qh  = wsu + 16 * M1;
  unsigned short* Kh  = wsu + 20 * M1;
  unsigned short* Vt  = wsu + 24 * M1;
  unsigned short* OutH= wsu + 28 * M1;

  dim3 tB(256);
  hipLaunchKernelGGL(cvt_all, dim3(8192), tB, 0, stream, query, key_, value, Wq, Wk, Wv, Wo,
                     Xq, Xk, Xv, Wqb, Wkb, Wvb, Wob);

  dim3 gG(DM / 128, MTOK / 128);  // (8, 32)
  hipLaunchKernelGGL((gemm_bf16<1>), gG, tB, 0, stream, Xq, Wqb, bq, (void*)Qh);
  hipLaunchKernelGGL((gemm_bf16<3>), gG, tB, 0, stream, Xk, Wkb, bk, (void*)Kh);
  hipLaunchKernelGGL((gemm_bf16<2>), gG, tB, 0, stream, Xv, Wvb, bv, (void*)Vt);

  hipLaunchKernelGGL(attn_mfma, dim3(64, 8), tB, 0, stream, Qh, Kh, Vt, attn, OutH);

  hipLaunchKernelGGL((gemm_bf16<0>), gG, tB, 0, stream, OutH, Wob, bo, (void*)out0);
}